// Round 8
// baseline (106.966 us; speedup 1.0000x reference)
//
#include <hip/hip_runtime.h>

// ---------------- problem constants ----------------
#define B_N  32
#define CI   128
#define CO   256
#define HP   66
#define WP   66
#define KTOT 1152
#define PIX  4096

#define XT_ELEMS ((size_t)B_N * HP * WP * CI)
#define XT_BYTES (XT_ELEMS * 2)
#define WT_BYTES ((size_t)CO * KTOT * 2)
#define WS_NEEDED (XT_BYTES + WT_BYTES)

#define AS1 __attribute__((address_space(1)))
#define AS3 __attribute__((address_space(3)))

typedef unsigned short us;
typedef __attribute__((ext_vector_type(8))) short bf16x8;
typedef __attribute__((ext_vector_type(4))) float f32x4;
typedef __attribute__((ext_vector_type(8))) unsigned short us8;

__device__ __forceinline__ us f2bf(float f) {
    unsigned int u = __builtin_bit_cast(unsigned int, f);
    u += 0x7fffu + ((u >> 16) & 1u);   // RNE
    return (us)(u >> 16);
}

__device__ __forceinline__ void gload16(const void* g, const void* l) {
    __builtin_amdgcn_global_load_lds((const AS1 unsigned int*)g,
                                     (AS3 unsigned int*)l, 16, 0, 0);
}

// -------- prologue: NCHW fp32 -> padded NHWC bf16 (+borders)
// -------- + distributed weight prep (144 elems/block, no serial tail) -------
__global__ void k_transpose(const float* __restrict__ X, const float* __restrict__ W,
                            us* __restrict__ Xt, us* __restrict__ Wt) {
    int bh   = blockIdx.x;
    int b    = bh >> 6, h = bh & 63;
    int wv   = threadIdx.x >> 6;
    int lane = threadIdx.x & 63;     // w
    const float* src = X + (((size_t)(b * CI + wv * 32) * 64 + h) << 6) + lane;
    us8 v[4];
#pragma unroll
    for (int j = 0; j < 32; ++j)
        v[j >> 3][j & 7] = f2bf(src[(size_t)j << 12]);
    us* dst = Xt + ((size_t)(b * HP + h + 1) * WP + (lane + 1)) * CI + wv * 32;
#pragma unroll
    for (int q = 0; q < 4; ++q)
        *(us8*)(dst + q * 8) = v[q];

    // distributed weight prep: 2048 blocks x 144 elems = 294912 = CO*KTOT
    int t = threadIdx.x;
    if (t < 144) {
        int g   = bh * 144 + t;
        int co  = g / KTOT, k = g - co * KTOT;
        int tap = k >> 7, ci = k & 127;
        Wt[g] = f2bf(W[((size_t)co * CI + ci) * 9 + tap]);
    }

    // border zeroing (replaces the 35.7MB memset)
    us8 z = (us8)0;
    if (t < 32) {
        int wcol = (t < 16) ? 0 : 65;
        int i = t & 15;
        *(us8*)(Xt + ((size_t)(b * HP + h + 1) * WP + wcol) * CI + i * 8) = z;
    }
    if (h == 0)
        for (int i = t; i < WP * CI / 8; i += 256)
            *(us8*)(Xt + (size_t)(b * HP + 0) * WP * CI + (size_t)i * 8) = z;
    if (h == 63)
        for (int i = t; i < WP * CI / 8; i += 256)
            *(us8*)(Xt + (size_t)(b * HP + 65) * WP * CI + (size_t)i * 8) = z;
}

// ---- main: 256co x 256px, BK=64, 8 waves (2Mx4N), 2-slot LDS dbuf,
// ---- 4 phases/K-tile, 1 half-tile staged/phase, counted vmcnt(6).
// ---- Readers remapped so ld*(slot,h) touches EXACTLY staging-half h:
// ----   A row = mh*128 + wm*64 + m*16 + lr ; B row = nh*128 + wn*32 + n*16 + lr
__global__ __launch_bounds__(512, 1) void k_conv_gemm(
    const us* __restrict__ Xt, const us* __restrict__ Wt,
    const float* __restrict__ bias, float* __restrict__ out) {

    __shared__ __attribute__((aligned(16))) us As[2][256 * 64];  // 64 KiB
    __shared__ __attribute__((aligned(16))) us Bs[2][256 * 64];  // 64 KiB

    const int bid0 = blockIdx.x;
    const int wg   = (bid0 & 7) * 64 + (bid0 >> 3);   // bijective XCD swizzle (512%8==0)
    const int b    = wg >> 4;
    const int nb   = wg & 15;
    const int h0   = nb << 2;            // 4 image rows per block

    const int tid  = threadIdx.x;
    const int lane = tid & 63;
    const int wv   = tid >> 6;
    const int lr   = lane & 15, lg = lane >> 4;
    const int wm   = wv >> 2,  wn = wv & 3;

    const int srow = tid >> 3;                 // 0..63
    const int sg   = (tid & 7) ^ (srow & 7);   // inverse-swizzled source group

    f32x4 acc[8][4] = {};
    bf16x8 a[4][2];          // current A half (4 m-frags x 2 kk)
    bf16x8 bb[2][2][2];      // both B halves resident [nh][n][kk]

    // one half-tile = 128 rows x 64 k = 16KB = 512 thr x 2 gloads x 16B
    auto stageA = [&](int slot, int t, int h) {
#pragma unroll
        for (int c = 0; c < 2; ++c) {
            const int row = h * 128 + c * 64 + srow;
            gload16(Wt + (size_t)row * KTOT + t * 64 + sg * 8,
                    &As[slot][(h * 128 + c * 64 + (wv << 3)) * 64]);
        }
    };
    auto stageB = [&](int slot, int t, int h) {
        const int tap = t >> 1;
        const int kh  = tap / 3, kw = tap - kh * 3;
        const int ci0 = (t & 1) << 6;
#pragma unroll
        for (int c = 0; c < 2; ++c) {
            const int p  = h * 128 + c * 64 + srow;      // tile-pixel 0..255
            const int hh = h0 + (p >> 6) + kh;           // padded row
            const int wc = (p & 63) + kw;                // padded col
            gload16(Xt + ((size_t)(b * HP + hh) * WP + wc) * CI + ci0 + sg * 8,
                    &Bs[slot][(h * 128 + c * 64 + (wv << 3)) * 64]);
        }
    };
    auto ldA = [&](int slot, int mh) {
#pragma unroll
        for (int m = 0; m < 4; ++m)
#pragma unroll
            for (int kk = 0; kk < 2; ++kk) {
                const int row = mh * 128 + wm * 64 + m * 16 + lr;   // within half mh only
                const int g   = ((kk << 2) + lg) ^ (row & 7);
                a[m][kk] = *(const bf16x8*)&As[slot][row * 64 + g * 8];
            }
    };
    auto ldB = [&](int slot, int nh) {
#pragma unroll
        for (int n = 0; n < 2; ++n)
#pragma unroll
            for (int kk = 0; kk < 2; ++kk) {
                const int row = nh * 128 + wn * 32 + n * 16 + lr;   // within half nh only
                const int g   = ((kk << 2) + lg) ^ (row & 7);
                bb[nh][n][kk] = *(const bf16x8*)&Bs[slot][row * 64 + g * 8];
            }
    };
    auto mma = [&](int mh, int nh) {
        asm volatile("s_waitcnt lgkmcnt(0)" ::: "memory");
        __builtin_amdgcn_sched_barrier(0);   // rule #18: fence MFMA behind the wait
        __builtin_amdgcn_s_setprio(1);
#pragma unroll
        for (int kk = 0; kk < 2; ++kk)
#pragma unroll
            for (int m = 0; m < 4; ++m)
#pragma unroll
                for (int n = 0; n < 2; ++n)
                    acc[mh * 4 + m][nh * 2 + n] = __builtin_amdgcn_mfma_f32_16x16x32_bf16(
                        a[m][kk], bb[nh][n][kk], acc[mh * 4 + m][nh * 2 + n], 0, 0, 0);
        __builtin_amdgcn_s_setprio(0);
    };

    // ---- pipeline prologue: tile0 complete + 3 half-tiles of tile1 ----
    stageA(0, 0, 0); stageB(0, 0, 0); stageB(0, 0, 1); stageA(0, 0, 1);
    stageA(1, 1, 0); stageB(1, 1, 0); stageB(1, 1, 1);
    asm volatile("s_waitcnt vmcnt(6)" ::: "memory");   // oldest 8 = all of tile0
    __builtin_amdgcn_s_barrier();

#pragma unroll
    for (int t = 0; t < 18; ++t) {
        const int s = t & 1, ns = s ^ 1;
        // P0: quadrant (mh0,nh0) — reads A-h0[s], B-h0[s]; stage A-h1 of tile t+1
        ldA(s, 0); ldB(s, 0);
        if (t + 1 < 18) stageA(ns, t + 1, 1);
        __builtin_amdgcn_s_barrier();
        mma(0, 0);
        __builtin_amdgcn_s_barrier();
        // P1: (mh0,nh1) — reads B-h1[s]; stage A-h0[s] for t+2 (A-h0[s] last read @P0)
        ldB(s, 1);
        if (t + 2 < 18) stageA(s, t + 2, 0);
        __builtin_amdgcn_s_barrier();
        mma(0, 1);
        __builtin_amdgcn_s_barrier();
        // P2: (mh1,nh1) — reads A-h1[s]; stage B-h0[s] for t+2 (B-h0[s] last read @P0)
        ldA(s, 1);
        if (t + 2 < 18) stageB(s, t + 2, 0);
        __builtin_amdgcn_s_barrier();
        mma(1, 1);
        __builtin_amdgcn_s_barrier();
        // P3: (mh1,nh0) from registers; stage B-h1[s] for t+2 (last read @P1)
        if (t + 2 < 18) stageB(s, t + 2, 1);
        __builtin_amdgcn_s_barrier();
        mma(1, 0);
        // per-K-tile counted guard: tile t+1's 8 loads are the oldest outstanding
        if (t < 16)       asm volatile("s_waitcnt vmcnt(6)" ::: "memory");
        else if (t == 16) asm volatile("s_waitcnt vmcnt(0)" ::: "memory");
        __builtin_amdgcn_s_barrier();
    }

    // epilogue: C/D frag col(pixel)=lane&15, row(co)=lg*4+j
    const int p0 = nb * 256;
#pragma unroll
    for (int mf = 0; mf < 8; ++mf) {
        const int mh = mf >> 2, m = mf & 3;
#pragma unroll
        for (int j = 0; j < 4; ++j) {
            const int co = mh * 128 + wm * 64 + m * 16 + lg * 4 + j;
            const float bv = bias[co];
            float* op = out + ((size_t)(b * CO + co) << 12) + p0 + wn * 32 + lr;
#pragma unroll
            for (int nf = 0; nf < 4; ++nf) {
                const int nh = nf >> 1, n = nf & 1;
                op[nh * 128 + n * 16] = acc[mf][nf][j] + bv;
            }
        }
    }
}

// ---------------- fallback: direct fp32 conv ----------------
__global__ void k_naive(const float* __restrict__ X, const float* __restrict__ W,
                        const float* __restrict__ bias, float* __restrict__ out) {
    long idx = (long)blockIdx.x * blockDim.x + threadIdx.x;
    if (idx >= (long)B_N * CO * PIX) return;
    int p = idx & 4095, co = (int)((idx >> 12) & 255), b = (int)(idx >> 20);
    int h = p >> 6, w = p & 63;
    float s = bias[co];
    for (int ci = 0; ci < CI; ++ci) {
        const float* xp = X + ((size_t)(b * CI + ci) << 12);
        const float* wp = W + ((size_t)(co * CI + ci)) * 9;
        for (int kh = 0; kh < 3; ++kh) {
            int hh2 = h + kh - 1; if ((unsigned)hh2 >= 64u) continue;
            for (int kw = 0; kw < 3; ++kw) {
                int ww2 = w + kw - 1; if ((unsigned)ww2 >= 64u) continue;
                s += xp[(hh2 << 6) + ww2] * wp[kh * 3 + kw];
            }
        }
    }
    out[idx] = s;
}

extern "C" void kernel_launch(void* const* d_in, const int* in_sizes, int n_in,
                              void* d_out, int out_size, void* d_ws, size_t ws_size,
                              hipStream_t stream) {
    const float* X    = (const float*)d_in[0];
    const float* W    = (const float*)d_in[1];
    const float* bias = (const float*)d_in[2];
    float* out = (float*)d_out;

    if (ws_size < WS_NEEDED) {
        long total = (long)B_N * CO * PIX;
        k_naive<<<(int)((total + 255) / 256), 256, 0, stream>>>(X, W, bias, out);
        return;
    }

    us* Xt = (us*)d_ws;
    us* Wt = (us*)((char*)d_ws + XT_BYTES);

    k_transpose<<<B_N * 64, 256, 0, stream>>>(X, W, Xt, Wt);
    k_conv_gemm<<<512, 512, 0, stream>>>(Xt, Wt, bias, out);
}

// Round 9
// 100.750 us; speedup vs baseline: 1.0617x; 1.0617x over previous
//
#include <hip/hip_runtime.h>

// ---------------- problem constants ----------------
#define B_N  32
#define CI   128
#define CO   256
#define HP   66
#define WP   66
#define KTOT 1152
#define PIX  4096

#define XT_ELEMS ((size_t)B_N * HP * WP * CI)
#define XT_BYTES (XT_ELEMS * 2)
#define WT_BYTES ((size_t)CO * KTOT * 2)
#define WS_NEEDED (XT_BYTES + WT_BYTES)

#define AS1 __attribute__((address_space(1)))
#define AS3 __attribute__((address_space(3)))

typedef unsigned short us;
typedef __attribute__((ext_vector_type(8))) short bf16x8;
typedef __attribute__((ext_vector_type(4))) float f32x4;
typedef __attribute__((ext_vector_type(8))) unsigned short us8;

__device__ __forceinline__ us f2bf(float f) {
    unsigned int u = __builtin_bit_cast(unsigned int, f);
    u += 0x7fffu + ((u >> 16) & 1u);   // RNE
    return (us)(u >> 16);
}

__device__ __forceinline__ void gload16(const void* g, const void* l) {
    __builtin_amdgcn_global_load_lds((const AS1 unsigned int*)g,
                                     (AS3 unsigned int*)l, 16, 0, 0);
}

// -------- prologue: NCHW fp32 -> padded NHWC bf16 (+borders), float4 reads --
// thread (wv,lg,li): ci = wv*32 + lg*8 + j (j=0..7), w = li*4 + dw (dw=0..3)
// reads: 8 x float4 (wave-instr = 4 contiguous 1KiB ci-rows); in-register
// 4wx8ci transpose; writes: 4 x us8 (64B contiguous per store).
__global__ void k_transpose(const float* __restrict__ X, const float* __restrict__ W,
                            us* __restrict__ Xt, us* __restrict__ Wt) {
    int bh   = blockIdx.x;           // 2048 = 32 b x 64 h
    int b    = bh >> 6, h = bh & 63;
    int wv   = threadIdx.x >> 6;
    int lane = threadIdx.x & 63;
    int lg   = lane >> 4;            // ci-octet within the wave's 32-ci slab
    int li   = lane & 15;            // w-quad

    const float* src = X + (((size_t)(b * CI + wv * 32 + lg * 8) * 64 + h) << 6) + li * 4;
    f32x4 f[8];
#pragma unroll
    for (int j = 0; j < 8; ++j)
        f[j] = *(const f32x4*)(src + (size_t)j * 4096);   // ci stride = 64*64

    us8 o[4];
#pragma unroll
    for (int dw = 0; dw < 4; ++dw)
#pragma unroll
        for (int e = 0; e < 8; ++e)
            o[dw][e] = f2bf(f[e][dw]);

    us* dstbase = Xt + ((size_t)(b * HP + h + 1) * WP + 1) * CI + wv * 32 + lg * 8;
#pragma unroll
    for (int dw = 0; dw < 4; ++dw)
        *(us8*)(dstbase + (size_t)(li * 4 + dw) * CI) = o[dw];

    // distributed weight prep: 2048 blocks x 144 elems = 294912 = CO*KTOT
    int t = threadIdx.x;
    if (t < 144) {
        int g   = bh * 144 + t;
        int co  = g / KTOT, k = g - co * KTOT;
        int tap = k >> 7, ci = k & 127;
        Wt[g] = f2bf(W[((size_t)co * CI + ci) * 9 + tap]);
    }

    // border zeroing (replaces the 35.7MB memset)
    us8 z = (us8)0;
    if (t < 32) {
        int wcol = (t < 16) ? 0 : 65;
        int i = t & 15;
        *(us8*)(Xt + ((size_t)(b * HP + h + 1) * WP + wcol) * CI + i * 8) = z;
    }
    if (h == 0)
        for (int i = t; i < WP * CI / 8; i += 256)
            *(us8*)(Xt + (size_t)(b * HP + 0) * WP * CI + (size_t)i * 8) = z;
    if (h == 63)
        for (int i = t; i < WP * CI / 8; i += 256)
            *(us8*)(Xt + (size_t)(b * HP + 65) * WP * CI + (size_t)i * 8) = z;
}

// ---- main: proven R6 structure — 128x128 tile, BK=64, 4 waves,
// ---- single-buffer 2-barrier K-loop, 16x16x32 MFMA, XOR swizzle,
// ---- K-loop fully unrolled (compile-time tap/kh/kw addressing) -------------
__global__ __launch_bounds__(256, 2) void k_conv_gemm(
    const us* __restrict__ Xt, const us* __restrict__ Wt,
    const float* __restrict__ bias, float* __restrict__ out) {

    __shared__ __attribute__((aligned(16))) us As[128 * 64];  // [co_local][k] 16KB
    __shared__ __attribute__((aligned(16))) us Bs[128 * 64];  // [p_local][k]  16KB

    const int bid = blockIdx.x;
    const int b   = bid >> 6;            // batch
    const int mb  = (bid >> 5) & 1;      // co block (2 of 128)
    const int nb  = bid & 31;            // p block (32 of 128)
    const int co0 = mb << 7;
    const int h0  = nb << 1;             // first output row of this p-block

    const int tid  = threadIdx.x;
    const int wv   = tid >> 6;
    const int lane = tid & 63;
    const int lr   = lane & 15;          // frag row/col
    const int lg   = lane >> 4;          // frag k-group
    const int wm   = wv >> 1, wn = wv & 1;

    const int srow = lane >> 3;               // staging: row within 8-row slab
    const int sg   = (lane & 7) ^ srow;       // inverse-swizzled source 16B-group

    f32x4 acc[4][4] = {};

#pragma unroll
    for (int s = 0; s < 18; ++s) {
        const int tap = s >> 1;
        const int ci0 = (s & 1) << 6;
        const int kh  = tap / 3;
        const int kw  = tap - kh * 3;
#pragma unroll
        for (int ii = 0; ii < 4; ++ii) {
            const int i = (wv << 2) + ii;                     // slab 0..15 (8 rows each)
            const int arow = co0 + (i << 3) + srow;
            gload16(Wt + (size_t)arow * KTOT + (s << 6) + (sg << 3), &As[i << 9]);
            const int pl = (i << 3) + srow;                   // p_local 0..127
            const int hh = h0 + (pl >> 6) + kh;               // padded row
            const int wc = (pl & 63) + kw;                    // padded col
            gload16(Xt + ((size_t)(b * HP + hh) * WP + wc) * CI + ci0 + (sg << 3),
                    &Bs[i << 9]);
        }
        __syncthreads();
#pragma unroll
        for (int kk = 0; kk < 2; ++kk) {
            bf16x8 af[4], bfr[4];
#pragma unroll
            for (int m = 0; m < 4; ++m) {
                const int row = (wm << 6) + (m << 4) + lr;
                const int g   = ((kk << 2) + lg) ^ (row & 7);   // swizzled read
                af[m] = *(const bf16x8*)&As[(row << 6) + (g << 3)];
            }
#pragma unroll
            for (int n = 0; n < 4; ++n) {
                const int row = (wn << 6) + (n << 4) + lr;
                const int g   = ((kk << 2) + lg) ^ (row & 7);
                bfr[n] = *(const bf16x8*)&Bs[(row << 6) + (g << 3)];
            }
#pragma unroll
            for (int m = 0; m < 4; ++m)
#pragma unroll
                for (int n = 0; n < 4; ++n)
                    acc[m][n] = __builtin_amdgcn_mfma_f32_16x16x32_bf16(
                        af[m], bfr[n], acc[m][n], 0, 0, 0);
        }
        __syncthreads();
    }

    // epilogue: C/D frag col = lane&15, row = (lane>>4)*4 + j  (m89-verified)
    const int p0 = nb << 7;
#pragma unroll
    for (int m = 0; m < 4; ++m) {
#pragma unroll
        for (int j = 0; j < 4; ++j) {
            const int co = co0 + (wm << 6) + (m << 4) + (lg << 2) + j;
            const float bv = bias[co];
            float* op = out + ((size_t)(b * CO + co) << 12) + p0 + (wn << 6) + lr;
#pragma unroll
            for (int n = 0; n < 4; ++n)
                op[n << 4] = acc[m][n][j] + bv;
        }
    }
}

// ---------------- fallback: direct fp32 conv ----------------
__global__ void k_naive(const float* __restrict__ X, const float* __restrict__ W,
                        const float* __restrict__ bias, float* __restrict__ out) {
    long idx = (long)blockIdx.x * blockDim.x + threadIdx.x;
    if (idx >= (long)B_N * CO * PIX) return;
    int p = idx & 4095, co = (int)((idx >> 12) & 255), b = (int)(idx >> 20);
    int h = p >> 6, w = p & 63;
    float s = bias[co];
    for (int ci = 0; ci < CI; ++ci) {
        const float* xp = X + ((size_t)(b * CI + ci) << 12);
        const float* wp = W + ((size_t)(co * CI + ci)) * 9;
        for (int kh = 0; kh < 3; ++kh) {
            int hh2 = h + kh - 1; if ((unsigned)hh2 >= 64u) continue;
            for (int kw = 0; kw < 3; ++kw) {
                int ww2 = w + kw - 1; if ((unsigned)ww2 >= 64u) continue;
                s += xp[(hh2 << 6) + ww2] * wp[kh * 3 + kw];
            }
        }
    }
    out[idx] = s;
}

extern "C" void kernel_launch(void* const* d_in, const int* in_sizes, int n_in,
                              void* d_out, int out_size, void* d_ws, size_t ws_size,
                              hipStream_t stream) {
    const float* X    = (const float*)d_in[0];
    const float* W    = (const float*)d_in[1];
    const float* bias = (const float*)d_in[2];
    float* out = (float*)d_out;

    if (ws_size < WS_NEEDED) {
        long total = (long)B_N * CO * PIX;
        k_naive<<<(int)((total + 255) / 256), 256, 0, stream>>>(X, W, bias, out);
        return;
    }

    us* Xt = (us*)d_ws;
    us* Wt = (us*)((char*)d_ws + XT_BYTES);

    k_transpose<<<B_N * 64, 256, 0, stream>>>(X, W, Xt, Wt);
    k_conv_gemm<<<B_N * 64, 256, 0, stream>>>(Xt, Wt, bias, out);
}